// Round 1
// baseline (44.963 us; speedup 1.0000x reference)
//
#include <hip/hip_runtime.h>

// Problem constants (from reference): B=32, C=4, L=512
constexpr int B = 32;
constexpr int C = 4;
constexpr int L = 512;
constexpr int THREADS = 256;
constexpr int ROWS_PER_BLOCK = 16;

// out[b*C+c] = sum_{x,y valid} receptor[b,c,x,y] * ligand[b,c,x-dx,y-dy]
// valid: dx <= x < L+dx (clamped to [0,L)), same for y with dy.
__global__ __launch_bounds__(THREADS)
void imgmul_kernel(const float* __restrict__ receptor,
                   const float* __restrict__ ligand,
                   const int* __restrict__ T,
                   float* __restrict__ out)
{
    const int bc = blockIdx.x;           // 0..B*C-1
    const int b  = bc / C;
    const int dx = T[2 * b + 0];
    const int dy = T[2 * b + 1];

    // Valid output-coordinate window
    const int x0 = dx > 0 ? dx : 0;
    const int x1 = (L + dx) < L ? (L + dx) : L;
    const int y0 = dy > 0 ? dy : 0;
    const int y1 = (L + dy) < L ? (L + dy) : L;

    const size_t plane = (size_t)bc * L * L;
    const float* rec = receptor + plane;
    const float* lig = ligand + plane;

    const int rbase = blockIdx.y * ROWS_PER_BLOCK;

    float acc = 0.0f;
    for (int r = 0; r < ROWS_PER_BLOCK; ++r) {
        const int x = rbase + r;
        if (x < x0 || x >= x1) continue;   // wave-uniform branch
        const float* rrow = rec + (size_t)x * L;
        // ligand row shifted: lrow[y] == ligand[x-dx][y-dy]
        const float* lrow = lig + (size_t)(x - dx) * L - dy;
        for (int y = y0 + (int)threadIdx.x; y < y1; y += THREADS) {
            acc += rrow[y] * lrow[y];
        }
    }

    // Wave-level reduce (64 lanes)
    #pragma unroll
    for (int off = 32; off > 0; off >>= 1)
        acc += __shfl_down(acc, off, 64);

    __shared__ float wsum[THREADS / 64];
    const int wid  = threadIdx.x >> 6;
    const int lane = threadIdx.x & 63;
    if (lane == 0) wsum[wid] = acc;
    __syncthreads();

    if (threadIdx.x == 0) {
        float s = wsum[0] + wsum[1] + wsum[2] + wsum[3];
        atomicAdd(&out[bc], s);
    }
}

extern "C" void kernel_launch(void* const* d_in, const int* in_sizes, int n_in,
                              void* d_out, int out_size, void* d_ws, size_t ws_size,
                              hipStream_t stream)
{
    const float* receptor = (const float*)d_in[0];
    const float* ligand   = (const float*)d_in[1];
    const int*   T        = (const int*)d_in[2];
    float* out = (float*)d_out;

    // d_out is poisoned by the harness and we accumulate with atomics:
    // zero it every launch (memset node is graph-capture safe).
    hipMemsetAsync(d_out, 0, (size_t)out_size * sizeof(float), stream);

    dim3 grid(B * C, L / ROWS_PER_BLOCK);
    imgmul_kernel<<<grid, dim3(THREADS), 0, stream>>>(receptor, ligand, T, out);
}

// Round 2
// 39.539 us; speedup vs baseline: 1.1372x; 1.1372x over previous
//
#include <hip/hip_runtime.h>

// Problem constants (from reference): B=32, C=4, L=512
constexpr int B = 32;
constexpr int C = 4;
constexpr int L = 512;
constexpr int THREADS = 256;          // 4 waves
constexpr int ROWS_PER_BLOCK = 16;    // 4 rows per wave

// Unaligned-tolerant 16B load (ligand side: base offset by -dy dwords).
__device__ inline float4 ld4u(const float* p) {
    float4 v;
    __builtin_memcpy(&v, p, sizeof(float4));
    return v;
}

// out[b*C+c] = sum_{x,y valid} receptor[b,c,x,y] * ligand[b,c,x-dx,y-dy]
__global__ __launch_bounds__(THREADS)
void imgmul_kernel(const float* __restrict__ receptor,
                   const float* __restrict__ ligand,
                   const int* __restrict__ T,
                   float* __restrict__ out)
{
    const int bc = blockIdx.x;           // 0..B*C-1
    const int b  = bc / C;
    const int dx = T[2 * b + 0];
    const int dy = T[2 * b + 1];

    // Valid window. |dx|,|dy| <= 256 -> window dims >= 256 (no degenerate cases).
    const int x0 = dx > 0 ? dx : 0;
    const int x1 = (L + dx) < L ? (L + dx) : L;
    const int y0 = dy > 0 ? dy : 0;
    const int y1 = (L + dy) < L ? (L + dy) : L;

    const size_t plane = (size_t)bc * L * L;
    const float* rec = receptor + plane;
    const float* lig = ligand + plane;

    const int wave = threadIdx.x >> 6;
    const int lane = threadIdx.x & 63;
    const int rbase = blockIdx.y * ROWS_PER_BLOCK;

    // Align quad grid to receptor rows (row base is 2KB-aligned).
    const int ya   = (y0 + 3) & ~3;
    const int head = ya - y0;            // 0..3 scalar columns at the front
    const int nq   = (y1 - ya) >> 2;     // full float4 quads
    const int rem  = (y1 - ya) & 3;      // 0..3 scalar columns at the back
    const int ytail = ya + 4 * nq;

    float acc = 0.0f;
    #pragma unroll
    for (int rr = 0; rr < ROWS_PER_BLOCK / 4; ++rr) {
        const int x = rbase + wave + 4 * rr;
        if (x < x0 || x >= x1) continue;            // wave-uniform
        const float* rrow = rec + (size_t)x * L;
        const float* lrow = lig + (size_t)(x - dx) * L - dy;  // lrow[y]=lig[x-dx][y-dy]

        if (lane < head)
            acc += rrow[y0 + lane] * lrow[y0 + lane];

        for (int q = lane; q < nq; q += 64) {
            const int y = ya + 4 * q;
            const float4 rv = *reinterpret_cast<const float4*>(rrow + y); // 16B-aligned
            const float4 lv = ld4u(lrow + y);                             // dword-aligned
            acc = fmaf(rv.x, lv.x, acc);
            acc = fmaf(rv.y, lv.y, acc);
            acc = fmaf(rv.z, lv.z, acc);
            acc = fmaf(rv.w, lv.w, acc);
        }

        if (lane < rem)
            acc += rrow[ytail + lane] * lrow[ytail + lane];
    }

    // Wave-level reduce (64 lanes)
    #pragma unroll
    for (int off = 32; off > 0; off >>= 1)
        acc += __shfl_down(acc, off, 64);

    __shared__ float wsum[THREADS / 64];
    if (lane == 0) wsum[wave] = acc;
    __syncthreads();

    if (threadIdx.x == 0) {
        float s = wsum[0] + wsum[1] + wsum[2] + wsum[3];
        atomicAdd(&out[bc], s);
    }
}

extern "C" void kernel_launch(void* const* d_in, const int* in_sizes, int n_in,
                              void* d_out, int out_size, void* d_ws, size_t ws_size,
                              hipStream_t stream)
{
    const float* receptor = (const float*)d_in[0];
    const float* ligand   = (const float*)d_in[1];
    const int*   T        = (const int*)d_in[2];
    float* out = (float*)d_out;

    // Atomic accumulation target: zero it every launch (graph-safe memset node).
    hipMemsetAsync(d_out, 0, (size_t)out_size * sizeof(float), stream);

    dim3 grid(B * C, L / ROWS_PER_BLOCK);
    imgmul_kernel<<<grid, dim3(THREADS), 0, stream>>>(receptor, ligand, T, out);
}